// Round 11
// baseline (2300.515 us; speedup 1.0000x reference)
//
#include <hip/hip_runtime.h>

// ConvGRU, fp16 MFMA implicit GEMM.
// R11: the dominant cost was PER-WAVE WEIGHT STREAMING from L2:
//   108KB/wave/cell x 8 waves x 1024 WGs ~= 885MB/dispatch ~= 26us at the
//   34.5TB/s L2 ceiling -- matching the idle-pipe gap (all pipes <40%).
// Fix:
//   - weights staged in LDS per K-step (dbuf, one barrier/step): L2 weight
//     traffic /8. prep_w emits FRAGMENT-LANE-MAJOR layout so the 512-thread
//     block copy and the per-lane ds_read_b128 fragment reads are both
//     linear (conflict-free, fully coalesced).
//   - state planes NOT staged: A-fragments read directly from the padded
//     global planes (L2-resident tiles; clamp positions identical to the
//     old staged path => bit-identical values). Deletes all DMA drains
//     (R10's vmcnt-ordering hazard class) and shrinks LDS 78.8->35KB ->
//     3-4 WG/CU (24-32 waves vs 16).
// Carried: R9 channel-pair cout permutation (paired 4B epilogue ops),
// 8x32 tile / 512 thr, schedule [L0(0)], 15x step_pair[L1||L0], [L1+emit].
// States fp16 NHWC padded planes [B][130][130][32], 1-px zero halo, ping-pong.

#define HH 128
#define PH 130
#define HW 16384
#define BB 8
#define TT 16

typedef _Float16 f16x8 __attribute__((ext_vector_type(8)));
typedef float f32x4 __attribute__((ext_vector_type(4)));
typedef unsigned int u32x4 __attribute__((ext_vector_type(4)));

__device__ __forceinline__ unsigned short f2h(float x){
    return __builtin_bit_cast(unsigned short, (_Float16)x);
}
__device__ __forceinline__ float h2f(unsigned short u){
    return (float)__builtin_bit_cast(_Float16, u);
}
__device__ __forceinline__ f16x8 ld_frag(const unsigned short* p){
    u32x4 v = *(const u32x4*)p;
    return __builtin_bit_cast(f16x8, v);
}
__device__ __forceinline__ f16x8 lds_frag_w(const unsigned short* base, int spix, int q){
    u32x4 v = *(const u32x4*)(base + spix * 32 + q * 8);
    return __builtin_bit_cast(f16x8, v);
}
__device__ __forceinline__ float sigmoid_f(float a){ return 1.0f / (1.0f + __expf(-a)); }
__device__ __forceinline__ float tanh_f(float a){ float e2 = __expf(2.0f * a); return 1.0f - 2.0f / (e2 + 1.0f); }
__device__ __forceinline__ unsigned int packh2(float lo, float hi){
    return (unsigned int)f2h(lo) | ((unsigned int)f2h(hi) << 16);
}

// A-fragment read straight from a padded global plane (L2-served).
// CLAMP=1 reproduces the old staged-path clamp positions bit-exactly.
template<int CLAMP>
__device__ __forceinline__ f16x8 gfrag(const unsigned short* __restrict__ g,
                                       int b, int pr, int pc, int q){
    if (CLAMP) {
        pr = pr < 0 ? 0 : (pr > PH - 1 ? PH - 1 : pr);
        pc = pc < 0 ? 0 : (pc > PH - 1 ? PH - 1 : pc);
    }
    return ld_frag(g + (long)((b * PH + pr) * PH + pc) * 32 + q * 8);
}

// LDS: weight dbuf (gates 2x4KB, cand 2x2KB) + rh + x tile = ~35KB
struct SmemT {
    unsigned short wg[2][2048];    //  8,192 B  gates weight blocks
    unsigned short wc[2][1024];    //  4,096 B  cand weight blocks
    unsigned short rh[10880];      // 21,760 B  r*h 10x34x32 (EMIT scratch too)
    float xt[444];                 //  1,776 B  x 12x37
};

// halo enumeration for 10x34 gates region: 84 px (rows 0,9 full; rows 1..8
// cols 0,33) as 6 16-px M-tiles; s>83 clamps (benign same-value dups).
__device__ __forceinline__ void halo_rc10(int s, int& gr, int& gc){
    s = s > 83 ? 83 : s;
    if (s < 34)      { gr = 0;            gc = s;      }
    else if (s < 68) { gr = 9;            gc = s - 34; }
    else if (s < 76) { gr = 1 + (s - 68); gc = 0;      }
    else             { gr = 1 + (s - 76); gc = 33;     }
}

// im2col x fragment for gates pixel (gr,gc); xt stride 37, origin R0-2,C0-2
__device__ __forceinline__ f16x8 x_im2col(const float* xt, int gr, int gc, int q){
    f16x8 v;
#pragma unroll
    for (int j = 0; j < 8; ++j) {
        int k = q * 8 + j;
        float f = 0.0f;
        if (k < 9) f = xt[(gr + k / 3) * 37 + gc + k % 3];
        v[j] = (_Float16)f;
    }
    return v;
}

// stage x(t) 12x37 fp32 tile (scalar loads)
__device__ __forceinline__ void stage_x12(float* xt, const float* __restrict__ seq,
                                          int b, int t, int R0, int C0)
{
    if (threadIdx.x < 444) {
        int p = threadIdx.x;
        int r = p / 37, c = p - r * 37;
        int ir = R0 - 2 + r, ic = C0 - 2 + c;
        float v = 0.0f;
        if (ir >= 0 && ir < HH && ic >= 0 && ic < HH)
            v = seq[((long)b * TT + t) * HW + ir * HH + ic];
        xt[p] = v;
    }
}

// ---- weight prep: [cout][cin_tot][9] fp32 -> FRAGMENT-LANE-MAJOR fp16 ----
// out idx = ((s*NG + ng)*64 + lane)*8 + j ; lane=(q<<4)|m16 ;
// physical row co = ng*16 + m16, k = q*8 + j. Channel-pair perm (R9):
// physical co holds LOGICAL cout (co&~31)|(2*(co&15)+((co>>4)&1)).
__global__ void prep_w(const float* __restrict__ w, unsigned short* __restrict__ wf,
                       int CO, int CIT, int NSTEP, int xmode)
{
    int idx = blockIdx.x * 256 + threadIdx.x;
    int total = NSTEP * CO * 32;
    if (idx >= total) return;
    int j  = idx & 7;
    int t  = idx >> 3;
    int l  = t & 63;
    int t2 = t >> 6;
    int NG = CO >> 4;
    int ng = t2 % NG;
    int s  = t2 / NG;
    int co = ng * 16 + (l & 15);
    int kk = (l >> 4) * 8 + j;
    int lco = (co & ~31) | (2 * (co & 15) + ((co >> 4) & 1));
    float v = 0.0f;
    if (xmode && s == NSTEP - 1) {
        if (kk < 9) v = w[(lco * CIT + 0) * 9 + kk];
    } else {
        int tap = s % 9;
        int cin = (s / 9) * 32 + kk + (xmode ? 1 : 0);
        v = w[(lco * CIT + cin) * 9 + tap];
    }
    wf[idx] = f2h(v);
}

// ---- cell compute. No plane staging: A-frags from global (L2). Weights
// stream through LDS dbuf, one barrier per K-step.
// L=0: x from xt (caller staged), h_old = Hp. L=1: x-part = Xp, h_old = Hp.
template<int L, int EMIT>
__device__ __forceinline__ void cell_compute(SmemT& sm,
    const unsigned short* __restrict__ Xp,
    const unsigned short* __restrict__ Hp,
    unsigned short* __restrict__ Hout,
    const unsigned short* __restrict__ Wg, const float* __restrict__ bg,
    const unsigned short* __restrict__ Wc, const float* __restrict__ bc,
    float* __restrict__ out, int b, int R0, int C0)
{
    constexpr int KG = (L == 0) ? 10 : 18;
    constexpr int KC = (L == 0) ? 10 : 18;

    const int tid = threadIdx.x;
    const int wv = tid >> 6, lane = tid & 63;
    const int m16 = lane & 15, q = lane >> 4;
    const int tid4 = tid * 4, tid2 = tid * 2, lane8 = lane * 8;

    // gates weight prologue: block 0 direct, block 1 into reg (in flight)
    *(unsigned long long*)(sm.wg[0] + tid4) =
        *(const unsigned long long*)(Wg + tid4);
    unsigned long long wng =
        *(const unsigned long long*)(Wg + 2048 + tid4);
    __syncthreads();   // wg[0] (+ xt for L0) visible

    // ---- phase 1: gates conv on 10x34 (16 interior + 6 halo tiles on
    // waves 2..7; halo = r-couts only). Thread's couts: logical 2*m16+ng.
    const bool HASH = (wv >= 2);
    int hgr = 0, hgc = 0;
    halo_rc10((wv - 2) * 16 + m16, hgr, hgc);

    f32x4 gI[2][4];
    f32x4 gH[2];
#pragma unroll
    for (int ng = 0; ng < 4; ++ng) {
        float bv = bg[(ng >> 1) * 32 + 2 * m16 + (ng & 1)];
#pragma unroll
        for (int mg = 0; mg < 2; ++mg) gI[mg][ng] = f32x4{bv, bv, bv, bv};
        if (ng < 2) gH[ng] = f32x4{bv, bv, bv, bv};
    }

#pragma unroll
    for (int s = 0; s < KG; ++s) {
        if (s + 1 < KG) {
            *(unsigned long long*)(sm.wg[(s + 1) & 1] + tid4) = wng;
            if (s + 2 < KG)
                wng = *(const unsigned long long*)(Wg + (s + 2) * 2048 + tid4);
        }
        f16x8 AI[2], AH;
        if (L == 0 && s == 9) {
#pragma unroll
            for (int mg = 0; mg < 2; ++mg)
                AI[mg] = x_im2col(sm.xt, wv + 1, mg * 16 + 1 + m16, q);
            AH = x_im2col(sm.xt, hgr, hgc, q);
        } else {
            const int tap = (L == 0) ? s : (s % 9);
            const unsigned short* pl = (L == 1 && s < 9) ? Xp : Hp;
            // interior: padded (R0+wv+tap/3, C0+mg*16+m16+tap%3) -- in-range
#pragma unroll
            for (int mg = 0; mg < 2; ++mg)
                AI[mg] = gfrag<0>(pl, b, R0 + wv + tap / 3,
                                  C0 + mg * 16 + m16 + tap % 3, q);
            // halo: padded (R0-1+hgr+tap/3, C0-1+hgc+tap%3) -- needs clamp
            AH = gfrag<1>(pl, b, R0 - 1 + hgr + tap / 3,
                          C0 - 1 + hgc + tap % 3, q);
        }
        f16x8 Bf[4];
#pragma unroll
        for (int ng = 0; ng < 4; ++ng)
            Bf[ng] = ld_frag(sm.wg[s & 1] + ng * 512 + lane8);
#pragma unroll
        for (int mg = 0; mg < 2; ++mg)
#pragma unroll
            for (int ng = 0; ng < 4; ++ng)
                gI[mg][ng] = __builtin_amdgcn_mfma_f32_16x16x32_f16(AI[mg], Bf[ng], gI[mg][ng], 0, 0, 0);
        if (HASH) {
#pragma unroll
            for (int ng = 0; ng < 2; ++ng)
                gH[ng] = __builtin_amdgcn_mfma_f32_16x16x32_f16(AH, Bf[ng], gH[ng], 0, 0, 0);
        }
        if (s + 1 < KG) __syncthreads();   // readers done before next overwrite
    }

    // gates epilogue. C layout: col=lane&15 (cout pair 2*m16,2*m16+1),
    // row(pixel)=q*4+rg. h reads: global plane, paired 4B. rh -> LDS.
    unsigned int zpk[2][4];
#pragma unroll
    for (int mg = 0; mg < 2; ++mg)
#pragma unroll
        for (int rg = 0; rg < 4; ++rg) {
            int gr = wv + 1, gc = mg * 16 + 1 + q * 4 + rg;
            zpk[mg][rg] = packh2(sigmoid_f(gI[mg][2][rg]), sigmoid_f(gI[mg][3][rg]));
            float rv0 = sigmoid_f(gI[mg][0][rg]);
            float rv1 = sigmoid_f(gI[mg][1][rg]);
            unsigned int hvp = *(const unsigned int*)(
                Hp + (long)((b * PH + R0 + gr) * PH + C0 + gc) * 32 + 2 * m16);
            float h0 = h2f((unsigned short)hvp), h1 = h2f((unsigned short)(hvp >> 16));
            *(unsigned int*)(sm.rh + (gr * 34 + gc) * 32 + 2 * m16) = packh2(rv0 * h0, rv1 * h1);
        }
    if (HASH) {
#pragma unroll
        for (int rg = 0; rg < 4; ++rg) {
            int gr, gc; halo_rc10((wv - 2) * 16 + q * 4 + rg, gr, gc);
            float rv0 = sigmoid_f(gH[0][rg]);
            float rv1 = sigmoid_f(gH[1][rg]);
            unsigned int hvp = *(const unsigned int*)(
                Hp + (long)((b * PH + R0 + gr) * PH + C0 + gc) * 32 + 2 * m16);
            float h0 = h2f((unsigned short)hvp), h1 = h2f((unsigned short)(hvp >> 16));
            *(unsigned int*)(sm.rh + (gr * 34 + gc) * 32 + 2 * m16) = packh2(rv0 * h0, rv1 * h1);
        }
    }

    // cand weight prologue (also the rh-visibility barrier)
    *(unsigned int*)(sm.wc[0] + tid2) = *(const unsigned int*)(Wc + tid2);
    unsigned int wnc = *(const unsigned int*)(Wc + 1024 + tid2);
    __syncthreads();   // rh + wc[0] visible

    // ---- phase 2: candidate conv on interior 8x32 (wave = 1 row, 2 m-tiles)
    f32x4 cacc[2][2];
#pragma unroll
    for (int mg = 0; mg < 2; ++mg)
#pragma unroll
        for (int ng = 0; ng < 2; ++ng) {
            float bv = bc[2 * m16 + ng];
            cacc[mg][ng] = f32x4{bv, bv, bv, bv};
        }
#pragma unroll
    for (int s = 0; s < KC; ++s) {
        if (s + 1 < KC) {
            *(unsigned int*)(sm.wc[(s + 1) & 1] + tid2) = wnc;
            if (s + 2 < KC)
                wnc = *(const unsigned int*)(Wc + (s + 2) * 1024 + tid2);
        }
        f16x8 A2[2];
        if (L == 0 && s == 9) {
#pragma unroll
            for (int mg = 0; mg < 2; ++mg)
                A2[mg] = x_im2col(sm.xt, wv + 1, mg * 16 + 1 + m16, q);
        } else if (L == 1 && s < 9) {
            // h0' taps: padded (R0+wv+s/3, C0+mg*16+m16+s%3) -- in-range
#pragma unroll
            for (int mg = 0; mg < 2; ++mg)
                A2[mg] = gfrag<0>(Xp, b, R0 + wv + s / 3,
                                  C0 + mg * 16 + m16 + s % 3, q);
        } else {
            const int tap = (L == 0) ? s : (s - 9);
#pragma unroll
            for (int mg = 0; mg < 2; ++mg)
                A2[mg] = lds_frag_w(sm.rh, (wv + tap / 3) * 34 + mg * 16 + m16 + tap % 3, q);
        }
        f16x8 Cf[2];
#pragma unroll
        for (int ng = 0; ng < 2; ++ng)
            Cf[ng] = ld_frag(sm.wc[s & 1] + ng * 512 + lane8);
#pragma unroll
        for (int mg = 0; mg < 2; ++mg)
#pragma unroll
            for (int ng = 0; ng < 2; ++ng)
                cacc[mg][ng] = __builtin_amdgcn_mfma_f32_16x16x32_f16(A2[mg], Cf[ng], cacc[mg][ng], 0, 0, 0);
        if (s + 1 < KC) __syncthreads();
    }

    // ---- update epilogue: h' = (1-z)*h_old + z*tanh(n); paired 4B ----
    unsigned int hvout[2][4];
#pragma unroll
    for (int mg = 0; mg < 2; ++mg)
#pragma unroll
        for (int rg = 0; rg < 4; ++rg) {
            int lcol = mg * 16 + q * 4 + rg;
            float nv0 = tanh_f(cacc[mg][0][rg]);
            float nv1 = tanh_f(cacc[mg][1][rg]);
            float zz0 = h2f((unsigned short)zpk[mg][rg]);
            float zz1 = h2f((unsigned short)(zpk[mg][rg] >> 16));
            unsigned int hop = *(const unsigned int*)(
                Hp + (long)((b * PH + R0 + wv + 1) * PH + C0 + lcol + 1) * 32 + 2 * m16);
            float ho0 = h2f((unsigned short)hop), ho1 = h2f((unsigned short)(hop >> 16));
            float hn0 = (1.0f - zz0) * ho0 + zz0 * nv0;
            float hn1 = (1.0f - zz1) * ho1 + zz1 * nv1;
            if (!EMIT) {
                long psp = (long)(b * PH + R0 + wv + 1) * PH + (C0 + lcol + 1);
                *(unsigned int*)(Hout + psp * 32 + 2 * m16) = packh2(hn0, hn1);
            } else {
                hvout[mg][rg] = packh2(hn0, hn1);
            }
        }

    if (EMIT) {
        // NCHW out via LDS transpose; rh dead after cand -> linear scratch.
        __syncthreads();
        unsigned short* scr = sm.rh;      // [8 rows][32 cols][32 ch]
#pragma unroll
        for (int mg = 0; mg < 2; ++mg)
#pragma unroll
            for (int rg = 0; rg < 4; ++rg)
                *(unsigned int*)(scr + ((wv * 32 + mg * 16 + q * 4 + rg) * 32) + 2 * m16)
                    = hvout[mg][rg];
        __syncthreads();
        const int rowid = tid >> 1, half = tid & 1;
        const int n = rowid >> 3, wr = rowid & 7;   // n = logical channel
        long obase = ((long)(b * 32 + n) * HH + (R0 + wr)) * HH + C0 + half * 16;
#pragma unroll
        for (int j = 0; j < 16; ++j)
            out[obase + j] = h2f(scr[(wr * 32 + half * 16 + j) * 32 + n]);
    }
}

// ---- solo L0 (t=0) ----
__global__ __launch_bounds__(512, 6)
void cell_l0(const unsigned short* __restrict__ Hin, unsigned short* __restrict__ Hout,
             const float* __restrict__ seq, int t,
             const unsigned short* __restrict__ Wg, const float* __restrict__ bg,
             const unsigned short* __restrict__ Wc, const float* __restrict__ bc)
{
    __shared__ __align__(16) SmemT sm;
    const int wg = blockIdx.x;
    const int b = wg >> 6, tr = (wg >> 2) & 15, tc = wg & 3;
    const int R0 = tr * 8, C0 = tc * 32;
    stage_x12(sm.xt, seq, b, t, R0, C0);
    cell_compute<0, 0>(sm, (const unsigned short*)0, Hin, Hout,
                       Wg, bg, Wc, bc, (float*)0, b, R0, C0);
}

// ---- merged pair: z=0 -> L1(t), z=1 -> L0(t+1); both read h0r ----
__global__ __launch_bounds__(512, 6)
void step_pair(const unsigned short* __restrict__ h1r, unsigned short* __restrict__ h1w,
               const unsigned short* __restrict__ h0r, unsigned short* __restrict__ h0w,
               const float* __restrict__ seq, int tnext,
               const unsigned short* __restrict__ WG0, const float* __restrict__ gb0,
               const unsigned short* __restrict__ WC0, const float* __restrict__ cb0,
               const unsigned short* __restrict__ WG1, const float* __restrict__ gb1,
               const unsigned short* __restrict__ WC1, const float* __restrict__ cb1)
{
    __shared__ __align__(16) SmemT sm;
    const int wg = blockIdx.x;
    const int b = wg >> 6, tr = (wg >> 2) & 15, tc = wg & 3;
    const int R0 = tr * 8, C0 = tc * 32;
    if (blockIdx.z == 0) {
        cell_compute<1, 0>(sm, h0r, h1r, h1w,
                           WG1, gb1, WC1, cb1, (float*)0, b, R0, C0);
    } else {
        stage_x12(sm.xt, seq, b, tnext, R0, C0);
        cell_compute<0, 0>(sm, (const unsigned short*)0, h0r, h0w,
                           WG0, gb0, WC0, cb0, (float*)0, b, R0, C0);
    }
}

// ---- final L1(T-1) with inline NCHW emit ----
__global__ __launch_bounds__(512, 6)
void cell_l1_emit(const unsigned short* __restrict__ Hin,
                  const unsigned short* __restrict__ Xin,
                  const unsigned short* __restrict__ Wg, const float* __restrict__ bg,
                  const unsigned short* __restrict__ Wc, const float* __restrict__ bc,
                  float* __restrict__ out)
{
    __shared__ __align__(16) SmemT sm;
    const int wg = blockIdx.x;
    const int b = wg >> 6, tr = (wg >> 2) & 15, tc = wg & 3;
    const int R0 = tr * 8, C0 = tc * 32;
    cell_compute<1, 1>(sm, Xin, Hin, (unsigned short*)0,
                       Wg, bg, Wc, bc, out, b, R0, C0);
}

extern "C" void kernel_launch(void* const* d_in, const int* in_sizes, int n_in,
                              void* d_out, int out_size, void* d_ws, size_t ws_size,
                              hipStream_t stream)
{
    const float* seq = (const float*)d_in[0];
    const float* gw0 = (const float*)d_in[1];
    const float* gb0 = (const float*)d_in[2];
    const float* cw0 = (const float*)d_in[3];
    const float* cb0 = (const float*)d_in[4];
    const float* gw1 = (const float*)d_in[5];
    const float* gb1 = (const float*)d_in[6];
    const float* cw1 = (const float*)d_in[7];
    const float* cb1 = (const float*)d_in[8];
    float* out = (float*)d_out;

    const size_t NSP = (size_t)BB * PH * PH * 32;    // 4,326,400 fp16 per plane

    char* p = (char*)d_ws;
    unsigned short* S0A = (unsigned short*)p; p += NSP * 2;
    unsigned short* S0B = (unsigned short*)p; p += NSP * 2;
    unsigned short* S1A = (unsigned short*)p; p += NSP * 2;
    unsigned short* S1B = (unsigned short*)p; p += NSP * 2;
    unsigned short* WG0 = (unsigned short*)p; p += 20480 * 2;
    unsigned short* WC0 = (unsigned short*)p; p += 10240 * 2;
    unsigned short* WG1 = (unsigned short*)p; p += 36864 * 2;
    unsigned short* WC1 = (unsigned short*)p; p += 18432 * 2;

    // zero all 4 state planes (h=0 init + permanent zero halos), one span
    hipMemsetAsync(S0A, 0, 4 * NSP * 2, stream);

    prep_w<<<(10 * 64 * 32 + 255) / 256, 256, 0, stream>>>(gw0, WG0, 64, 33, 10, 1);
    prep_w<<<(10 * 32 * 32 + 255) / 256, 256, 0, stream>>>(cw0, WC0, 32, 33, 10, 1);
    prep_w<<<(18 * 64 * 32 + 255) / 256, 256, 0, stream>>>(gw1, WG1, 64, 64, 18, 0);
    prep_w<<<(18 * 32 * 32 + 255) / 256, 256, 0, stream>>>(cw1, WC1, 32, 64, 18, 0);

    dim3 grid1(512, 1, 1), grid2(512, 1, 2), block(512);

    // t=0, layer 0: reads S0A (zeros) writes S0B
    cell_l0<<<grid1, block, 0, stream>>>(S0A, S0B, seq, 0, WG0, gb0, WC0, cb0);

    // merged pairs: dispatch k runs L1(t=k) and L0(t=k+1)
    unsigned short *h0r = S0B, *h0w = S0A, *h1r = S1A, *h1w = S1B;
    for (int t = 0; t < TT - 1; ++t) {
        step_pair<<<grid2, block, 0, stream>>>(h1r, h1w, h0r, h0w, seq, t + 1,
                                               WG0, gb0, WC0, cb0,
                                               WG1, gb1, WC1, cb1);
        unsigned short* tmp;
        tmp = h0r; h0r = h0w; h0w = tmp;
        tmp = h1r; h1r = h1w; h1w = tmp;
    }
    // final: L1(15) reads h1r + h0r (h0'(15)), emits NCHW fp32 out
    cell_l1_emit<<<grid1, block, 0, stream>>>(h1r, h0r, WG1, gb1, WC1, cb1, out);
}

// Round 12
// 974.598 us; speedup vs baseline: 2.3605x; 2.3605x over previous
//
#include <hip/hip_runtime.h>

// ConvGRU, fp16 MFMA implicit GEMM.
// R12 = R9 (best structure, 972us) + INTERLEAVED-DMA deferred hs1 staging.
// R10 lesson: vmcnt is one in-order queue; DMA issued BEFORE the gates
// loop's weight loads forces a full drain at every weight wait (64->72us,
// FETCH 2x). R11 lesson: the fabric sustains 3.4TB/s when requests spread
// through the kernel -- the staged path's 600GB/s is burstiness.
// Fix: L1 roles stage hs0, barrier, then issue hs1's 27 DMA chunks INSIDE
// gates steps s=0..3, AFTER each step's weight prefetch (chunk wv+8*s).
// Weight waits then cover only OLDER loads -> counted vmcnt leaves the DMA
// in flight; hs1's drain hides under 9 gate K-steps; barrier before s=9
// (first hs1 reader). L0 role unchanged.
// Carried from R9: channel-pair cout permutation (paired 4B epilogue ops),
// pre-barrier weight-frag issue, reg-dbuf weights, 8x32 tile / 512 thr.
// Schedule: [L0(0)], 15x step_pair[L1(t) || L0(t+1)] (grid.z), [L1(15)+emit].
// States fp16 NHWC padded planes [B][130][130][32], 1-px zero halo, ping-pong.
// Stage tile 12x36 (2-px halo) via global_load_lds; clamped rows/cols land in
// the zero halo ring == SAME-pad value.

#define HH 128
#define PH 130
#define HW 16384
#define BB 8
#define TT 16

typedef _Float16 f16x8 __attribute__((ext_vector_type(8)));
typedef float f32x4 __attribute__((ext_vector_type(4)));
typedef unsigned int u32x4 __attribute__((ext_vector_type(4)));

__device__ __forceinline__ unsigned short f2h(float x){
    return __builtin_bit_cast(unsigned short, (_Float16)x);
}
__device__ __forceinline__ float h2f(unsigned short u){
    return (float)__builtin_bit_cast(_Float16, u);
}
__device__ __forceinline__ f16x8 ld_frag(const unsigned short* p){
    u32x4 v = *(const u32x4*)p;
    return __builtin_bit_cast(f16x8, v);
}
__device__ __forceinline__ f16x8 lds_frag_w(const unsigned short* base, int spix, int q){
    u32x4 v = *(const u32x4*)(base + spix * 32 + q * 8);
    return __builtin_bit_cast(f16x8, v);
}
__device__ __forceinline__ float sigmoid_f(float a){ return 1.0f / (1.0f + __expf(-a)); }
__device__ __forceinline__ float tanh_f(float a){ float e2 = __expf(2.0f * a); return 1.0f - 2.0f / (e2 + 1.0f); }
__device__ __forceinline__ unsigned int packh2(float lo, float hi){
    return (unsigned int)f2h(lo) | ((unsigned int)f2h(hi) << 16);
}

// LDS block: 2 stage planes 12x36x32 fp16 + rh 10x34x32 fp16 + x 12x37 fp32
struct SmemT {
    unsigned short hs[2][13824];   // 55,296 B
    unsigned short rh[10880];      // 21,760 B (also out-transpose scratch)
    float xt[444];                 //  1,776 B   => 78,832 B total
};

// halo enumeration for 10x34 gates region: 84 px (rows 0,9 full; rows 1..8
// cols 0,33) as 6 16-px M-tiles; s>83 clamps (benign same-value dups).
__device__ __forceinline__ void halo_rc10(int s, int& gr, int& gc){
    s = s > 83 ? 83 : s;
    if (s < 34)      { gr = 0;            gc = s;      }
    else if (s < 68) { gr = 9;            gc = s - 34; }
    else if (s < 76) { gr = 1 + (s - 68); gc = 0;      }
    else             { gr = 1 + (s - 76); gc = 33;     }
}

// im2col x fragment for gates pixel (gr,gc); xt stride 37, origin R0-2,C0-2
__device__ __forceinline__ f16x8 x_im2col(const float* xt, int gr, int gc, int q){
    f16x8 v;
#pragma unroll
    for (int j = 0; j < 8; ++j) {
        int k = q * 8 + j;
        float f = 0.0f;
        if (k < 9) f = xt[(gr + k / 3) * 37 + gc + k % 3];
        v[j] = (_Float16)f;
    }
    return v;
}

// issue ONE 16B DMA chunk (k in [0,27)) of a 12x36 plane tile
__device__ __forceinline__ void stage_chunk(unsigned short* slot,
    const unsigned short* __restrict__ g, int b, int pr0, int pc0, int k, int lane)
{
    int chunk = k * 64 + lane;
    int pix = chunk >> 2, part = chunk & 3;
    int r = pix / 36, c = pix - r * 36;
    int pr = pr0 + r; pr = pr < 0 ? 0 : (pr > 129 ? 129 : pr);
    int pc = pc0 + c; pc = pc < 0 ? 0 : (pc > 129 ? 129 : pc);
    const unsigned short* ga = g + ((long)((b * PH + pr) * PH + pc) * 32 + part * 8);
    __builtin_amdgcn_global_load_lds(
        (const __attribute__((address_space(1))) unsigned int*)ga,
        (__attribute__((address_space(3))) unsigned int*)(slot + k * 512),
        16, 0, 0);
}

// ---- async DMA staging: whole 12x36 tile = 27 chunks ----
__device__ __forceinline__ void stage_plane12(unsigned short* slot,
    const unsigned short* __restrict__ g, int b, int pr0, int pc0)
{
    const int wv = threadIdx.x >> 6, lane = threadIdx.x & 63;
    for (int k = wv; k < 27; k += 8)
        stage_chunk(slot, g, b, pr0, pc0, k, lane);
}

// stage x(t) 12x37 fp32 tile (scalar loads)
__device__ __forceinline__ void stage_x12(float* xt, const float* __restrict__ seq,
                                          int b, int t, int R0, int C0)
{
    if (threadIdx.x < 444) {
        int p = threadIdx.x;
        int r = p / 37, c = p - r * 37;
        int ir = R0 - 2 + r, ic = C0 - 2 + c;
        float v = 0.0f;
        if (ir >= 0 && ir < HH && ic >= 0 && ic < HH)
            v = seq[((long)b * TT + t) * HW + ir * HH + ic];
        xt[p] = v;
    }
}

// ---- weight prep: [cout][cin_tot][9] fp32 -> [step][cout_phys][32] fp16 ----
// Row permutation: physical row i holds LOGICAL cout
//   lco = (i & ~31) | (2*(i&15) + ((i>>4)&1))
// so MFMA thread (ng,m16) owns logical channels {2*m16+ng} (adjacent pair).
__global__ void prep_w(const float* __restrict__ w, unsigned short* __restrict__ wf,
                       int CO, int CIT, int NSTEP, int xmode)
{
    int idx = blockIdx.x * 256 + threadIdx.x;
    int total = NSTEP * CO * 32;
    if (idx >= total) return;
    int kk = idx & 31;
    int t  = idx >> 5;
    int co = t % CO;
    int s  = t / CO;
    int lco = (co & ~31) | (2 * (co & 15) + ((co >> 4) & 1));
    float v = 0.0f;
    if (xmode && s == NSTEP - 1) {
        if (kk < 9) v = w[(lco * CIT + 0) * 9 + kk];
    } else {
        int tap = s % 9;
        int cin = (s / 9) * 32 + kk + (xmode ? 1 : 0);
        v = w[(lco * CIT + cin) * 9 + tap];
    }
    wf[idx] = f2h(v);
}

// ---- cell compute. Caller stages hs0 (+xt for L0); first barrier INSIDE.
// SPLIT=1 (L1 roles): hs1's DMA chunks are issued inside gates steps s=0..3
// AFTER each step's weight prefetch (vmcnt-order-safe); barrier before s=9.
template<int L, int EMIT, int SPLIT>
__device__ __forceinline__ void cell_compute(SmemT& sm,
    const unsigned short* __restrict__ hs1src,
    unsigned short* __restrict__ Hout,
    const unsigned short* __restrict__ Wg, const float* __restrict__ bg,
    const unsigned short* __restrict__ Wc, const float* __restrict__ bc,
    float* __restrict__ out, int b, int R0, int C0)
{
    constexpr int KG = (L == 0) ? 10 : 18;
    constexpr int KC = (L == 0) ? 10 : 18;

    const int wv = threadIdx.x >> 6, lane = threadIdx.x & 63;
    const int m16 = lane & 15, q = lane >> 4;
    const unsigned short* hp = (L == 0) ? sm.hs[0] : sm.hs[1];

    // pre-barrier weight issue: s=0 gates frags + s=0 cand frags
    f16x8 Bc[4];
#pragma unroll
    for (int ng = 0; ng < 4; ++ng)
        Bc[ng] = ld_frag(Wg + (ng * 16 + m16) * 32 + q * 8);
    f16x8 Cc[2];
#pragma unroll
    for (int ng = 0; ng < 2; ++ng)
        Cc[ng] = ld_frag(Wc + (ng * 16 + m16) * 32 + q * 8);

    __syncthreads();   // drains hs0 staging (+ weight loads)

    // ---- phase 1: gates conv on 10x34 (16 interior tiles + 6 halo tiles on
    // waves 2..7; halo = r-couts only). Thread's couts: logical 2*m16+ng. ----
    const bool HASH = (wv >= 2);
    int hgr = 0, hgc = 0;
    halo_rc10((wv - 2) * 16 + m16, hgr, hgc);

    f32x4 gI[2][4];
    f32x4 gH[2];
#pragma unroll
    for (int ng = 0; ng < 4; ++ng) {
        float bv = bg[(ng >> 1) * 32 + 2 * m16 + (ng & 1)];
#pragma unroll
        for (int mg = 0; mg < 2; ++mg) gI[mg][ng] = f32x4{bv, bv, bv, bv};
        if (ng < 2) gH[ng] = f32x4{bv, bv, bv, bv};
    }

#pragma unroll
    for (int s = 0; s < KG; ++s) {
        if (SPLIT && s == 9) __syncthreads();   // hs1 DMA drained (vmcnt(0))
        f16x8 Bn[4];
        if (s + 1 < KG) {
#pragma unroll
            for (int ng = 0; ng < 4; ++ng)
                Bn[ng] = ld_frag(Wg + ((s + 1) * 64 + ng * 16 + m16) * 32 + q * 8);
        }
        // interleaved hs1 DMA: chunk wv+8*s at steps 0..3, AFTER this step's
        // weight prefetch -> weight waits never drain the DMA queue.
        if (SPLIT && s < 4) {
            int k = wv + 8 * s;
            if (k < 27)
                stage_chunk(sm.hs[1], hs1src, b, R0 - 1, C0 - 1, k, lane);
        }
        f16x8 AI[2], AH;
        if (L == 0 && s == 9) {
#pragma unroll
            for (int mg = 0; mg < 2; ++mg)
                AI[mg] = x_im2col(sm.xt, wv + 1, mg * 16 + 1 + m16, q);
            AH = x_im2col(sm.xt, hgr, hgc, q);
        } else {
            const int tap = (L == 0) ? s : (s % 9);
            const unsigned short* pl = (L == 1 && s >= 9) ? sm.hs[1] : sm.hs[0];
#pragma unroll
            for (int mg = 0; mg < 2; ++mg)
                AI[mg] = lds_frag_w(pl, (wv + 1 + tap / 3) * 36 + mg * 16 + 1 + m16 + tap % 3, q);
            AH = lds_frag_w(pl, (hgr + tap / 3) * 36 + hgc + tap % 3, q);
        }
#pragma unroll
        for (int mg = 0; mg < 2; ++mg)
#pragma unroll
            for (int ng = 0; ng < 4; ++ng)
                gI[mg][ng] = __builtin_amdgcn_mfma_f32_16x16x32_f16(AI[mg], Bc[ng], gI[mg][ng], 0, 0, 0);
        if (HASH) {
#pragma unroll
            for (int ng = 0; ng < 2; ++ng)
                gH[ng] = __builtin_amdgcn_mfma_f32_16x16x32_f16(AH, Bc[ng], gH[ng], 0, 0, 0);
        }
        if (s + 1 < KG) {
#pragma unroll
            for (int ng = 0; ng < 4; ++ng) Bc[ng] = Bn[ng];
        }
    }

    // gates epilogue. C layout: col=lane&15 (-> cout pair 2*m16,2*m16+1),
    // row(pixel)=q*4+rg. All h/rh accesses PAIRED 4B at channel 2*m16.
    unsigned int zpk[2][4];
#pragma unroll
    for (int mg = 0; mg < 2; ++mg)
#pragma unroll
        for (int rg = 0; rg < 4; ++rg) {
            int gr = wv + 1, gc = mg * 16 + 1 + q * 4 + rg;
            zpk[mg][rg] = packh2(sigmoid_f(gI[mg][2][rg]), sigmoid_f(gI[mg][3][rg]));
            float rv0 = sigmoid_f(gI[mg][0][rg]);
            float rv1 = sigmoid_f(gI[mg][1][rg]);
            unsigned int hvp = *(const unsigned int*)(hp + ((gr + 1) * 36 + gc + 1) * 32 + 2 * m16);
            float h0 = h2f((unsigned short)hvp), h1 = h2f((unsigned short)(hvp >> 16));
            *(unsigned int*)(sm.rh + (gr * 34 + gc) * 32 + 2 * m16) = packh2(rv0 * h0, rv1 * h1);
        }
    if (HASH) {
#pragma unroll
        for (int rg = 0; rg < 4; ++rg) {
            int gr, gc; halo_rc10((wv - 2) * 16 + q * 4 + rg, gr, gc);
            float rv0 = sigmoid_f(gH[0][rg]);
            float rv1 = sigmoid_f(gH[1][rg]);
            unsigned int hvp = *(const unsigned int*)(hp + ((gr + 1) * 36 + gc + 1) * 32 + 2 * m16);
            float h0 = h2f((unsigned short)hvp), h1 = h2f((unsigned short)(hvp >> 16));
            *(unsigned int*)(sm.rh + (gr * 34 + gc) * 32 + 2 * m16) = packh2(rv0 * h0, rv1 * h1);
        }
    }
    __syncthreads();

    // ---- phase 2: candidate conv on interior 8x32 (wave = 1 row, 2 m-tiles)
    f32x4 cacc[2][2];
#pragma unroll
    for (int mg = 0; mg < 2; ++mg)
#pragma unroll
        for (int ng = 0; ng < 2; ++ng) {
            float bv = bc[2 * m16 + ng];
            cacc[mg][ng] = f32x4{bv, bv, bv, bv};
        }
#pragma unroll
    for (int s = 0; s < KC; ++s) {
        f16x8 Cn[2];
        if (s + 1 < KC) {
#pragma unroll
            for (int ng = 0; ng < 2; ++ng)
                Cn[ng] = ld_frag(Wc + ((s + 1) * 32 + ng * 16 + m16) * 32 + q * 8);
        }
        f16x8 A2[2];
        if (L == 0 && s == 9) {
#pragma unroll
            for (int mg = 0; mg < 2; ++mg)
                A2[mg] = x_im2col(sm.xt, wv + 1, mg * 16 + 1 + m16, q);
        } else if (L == 1 && s < 9) {
#pragma unroll
            for (int mg = 0; mg < 2; ++mg)
                A2[mg] = lds_frag_w(sm.hs[0], (wv + 1 + s / 3) * 36 + mg * 16 + m16 + 1 + s % 3, q);
        } else {
            const int tap = (L == 0) ? s : (s - 9);
#pragma unroll
            for (int mg = 0; mg < 2; ++mg)
                A2[mg] = lds_frag_w(sm.rh, (wv + tap / 3) * 34 + mg * 16 + m16 + tap % 3, q);
        }
#pragma unroll
        for (int mg = 0; mg < 2; ++mg)
#pragma unroll
            for (int ng = 0; ng < 2; ++ng)
                cacc[mg][ng] = __builtin_amdgcn_mfma_f32_16x16x32_f16(A2[mg], Cc[ng], cacc[mg][ng], 0, 0, 0);
        if (s + 1 < KC) {
#pragma unroll
            for (int ng = 0; ng < 2; ++ng) Cc[ng] = Cn[ng];
        }
    }

    // ---- update epilogue: h' = (1-z)*h_old + z*tanh(n); all paired 4B ----
    unsigned int hvout[2][4];
#pragma unroll
    for (int mg = 0; mg < 2; ++mg)
#pragma unroll
        for (int rg = 0; rg < 4; ++rg) {
            int lcol = mg * 16 + q * 4 + rg;
            float nv0 = tanh_f(cacc[mg][0][rg]);
            float nv1 = tanh_f(cacc[mg][1][rg]);
            float zz0 = h2f((unsigned short)zpk[mg][rg]);
            float zz1 = h2f((unsigned short)(zpk[mg][rg] >> 16));
            unsigned int hop = *(const unsigned int*)(hp + ((wv + 2) * 36 + lcol + 2) * 32 + 2 * m16);
            float ho0 = h2f((unsigned short)hop), ho1 = h2f((unsigned short)(hop >> 16));
            float hn0 = (1.0f - zz0) * ho0 + zz0 * nv0;
            float hn1 = (1.0f - zz1) * ho1 + zz1 * nv1;
            if (!EMIT) {
                long psp = (long)(b * PH + R0 + wv + 1) * PH + (C0 + lcol + 1);
                *(unsigned int*)(Hout + psp * 32 + 2 * m16) = packh2(hn0, hn1);
            } else {
                hvout[mg][rg] = packh2(hn0, hn1);
            }
        }

    if (EMIT) {
        // NCHW out via LDS transpose; rh dead after cand -> linear scratch.
        __syncthreads();
        unsigned short* scr = sm.rh;      // [8 rows][32 cols][32 ch]
#pragma unroll
        for (int mg = 0; mg < 2; ++mg)
#pragma unroll
            for (int rg = 0; rg < 4; ++rg)
                *(unsigned int*)(scr + ((wv * 32 + mg * 16 + q * 4 + rg) * 32) + 2 * m16)
                    = hvout[mg][rg];
        __syncthreads();
        const int tid = threadIdx.x;
        const int rowid = tid >> 1, half = tid & 1;
        const int n = rowid >> 3, wr = rowid & 7;   // n = logical channel
        long obase = ((long)(b * 32 + n) * HH + (R0 + wr)) * HH + C0 + half * 16;
#pragma unroll
        for (int j = 0; j < 16; ++j)
            out[obase + j] = h2f(scr[(wr * 32 + half * 16 + j) * 32 + n]);
    }
}

// ---- solo L0 (t=0): stage h0 + x, compute ----
__global__ __launch_bounds__(512, 4)
void cell_l0(const unsigned short* __restrict__ Hin, unsigned short* __restrict__ Hout,
             const float* __restrict__ seq, int t,
             const unsigned short* __restrict__ Wg, const float* __restrict__ bg,
             const unsigned short* __restrict__ Wc, const float* __restrict__ bc)
{
    __shared__ __align__(16) SmemT sm;
    const int wg = blockIdx.x;
    const int b = wg >> 6, tr = (wg >> 2) & 15, tc = wg & 3;
    const int R0 = tr * 8, C0 = tc * 32;
    stage_x12(sm.xt, seq, b, t, R0, C0);
    stage_plane12(sm.hs[0], Hin, b, R0 - 1, C0 - 1);
    cell_compute<0, 0, 0>(sm, (const unsigned short*)0, Hout,
                          Wg, bg, Wc, bc, (float*)0, b, R0, C0);
}

// ---- merged pair: z=0 -> L1(t) (interleaved split stage), z=1 -> L0(t+1) ----
__global__ __launch_bounds__(512, 4)
void step_pair(const unsigned short* __restrict__ h1r, unsigned short* __restrict__ h1w,
               const unsigned short* __restrict__ h0r, unsigned short* __restrict__ h0w,
               const float* __restrict__ seq, int tnext,
               const unsigned short* __restrict__ WG0, const float* __restrict__ gb0,
               const unsigned short* __restrict__ WC0, const float* __restrict__ cb0,
               const unsigned short* __restrict__ WG1, const float* __restrict__ gb1,
               const unsigned short* __restrict__ WC1, const float* __restrict__ cb1)
{
    __shared__ __align__(16) SmemT sm;
    const int wg = blockIdx.x;
    const int b = wg >> 6, tr = (wg >> 2) & 15, tc = wg & 3;
    const int R0 = tr * 8, C0 = tc * 32;
    if (blockIdx.z == 0) {
        stage_plane12(sm.hs[0], h0r, b, R0 - 1, C0 - 1);   // h0'(t): x-part of L1
        cell_compute<1, 0, 1>(sm, h1r, h1w,                // hs1=h1(t), in-loop DMA
                              WG1, gb1, WC1, cb1, (float*)0, b, R0, C0);
    } else {
        stage_x12(sm.xt, seq, b, tnext, R0, C0);
        stage_plane12(sm.hs[0], h0r, b, R0 - 1, C0 - 1);   // h-old of L0
        cell_compute<0, 0, 0>(sm, (const unsigned short*)0, h0w,
                              WG0, gb0, WC0, cb0, (float*)0, b, R0, C0);
    }
}

// ---- final L1(T-1) with inline NCHW emit (interleaved split stage) ----
__global__ __launch_bounds__(512, 4)
void cell_l1_emit(const unsigned short* __restrict__ Hin,
                  const unsigned short* __restrict__ Xin,
                  const unsigned short* __restrict__ Wg, const float* __restrict__ bg,
                  const unsigned short* __restrict__ Wc, const float* __restrict__ bc,
                  float* __restrict__ out)
{
    __shared__ __align__(16) SmemT sm;
    const int wg = blockIdx.x;
    const int b = wg >> 6, tr = (wg >> 2) & 15, tc = wg & 3;
    const int R0 = tr * 8, C0 = tc * 32;
    stage_plane12(sm.hs[0], Xin, b, R0 - 1, C0 - 1);
    cell_compute<1, 1, 1>(sm, Hin, (unsigned short*)0,
                          Wg, bg, Wc, bc, out, b, R0, C0);
}

extern "C" void kernel_launch(void* const* d_in, const int* in_sizes, int n_in,
                              void* d_out, int out_size, void* d_ws, size_t ws_size,
                              hipStream_t stream)
{
    const float* seq = (const float*)d_in[0];
    const float* gw0 = (const float*)d_in[1];
    const float* gb0 = (const float*)d_in[2];
    const float* cw0 = (const float*)d_in[3];
    const float* cb0 = (const float*)d_in[4];
    const float* gw1 = (const float*)d_in[5];
    const float* gb1 = (const float*)d_in[6];
    const float* cw1 = (const float*)d_in[7];
    const float* cb1 = (const float*)d_in[8];
    float* out = (float*)d_out;

    const size_t NSP = (size_t)BB * PH * PH * 32;    // 4,326,400 fp16 per plane

    char* p = (char*)d_ws;
    unsigned short* S0A = (unsigned short*)p; p += NSP * 2;
    unsigned short* S0B = (unsigned short*)p; p += NSP * 2;
    unsigned short* S1A = (unsigned short*)p; p += NSP * 2;
    unsigned short* S1B = (unsigned short*)p; p += NSP * 2;
    unsigned short* WG0 = (unsigned short*)p; p += 20480 * 2;
    unsigned short* WC0 = (unsigned short*)p; p += 10240 * 2;
    unsigned short* WG1 = (unsigned short*)p; p += 36864 * 2;
    unsigned short* WC1 = (unsigned short*)p; p += 18432 * 2;

    // zero all 4 state planes (h=0 init + permanent zero halos), one span
    hipMemsetAsync(S0A, 0, 4 * NSP * 2, stream);

    prep_w<<<(10 * 64 * 32 + 255) / 256, 256, 0, stream>>>(gw0, WG0, 64, 33, 10, 1);
    prep_w<<<(10 * 32 * 32 + 255) / 256, 256, 0, stream>>>(cw0, WC0, 32, 33, 10, 1);
    prep_w<<<(18 * 64 * 32 + 255) / 256, 256, 0, stream>>>(gw1, WG1, 64, 64, 18, 0);
    prep_w<<<(18 * 32 * 32 + 255) / 256, 256, 0, stream>>>(cw1, WC1, 32, 64, 18, 0);

    dim3 grid1(512, 1, 1), grid2(512, 1, 2), block(512);

    // t=0, layer 0: reads S0A (zeros) writes S0B
    cell_l0<<<grid1, block, 0, stream>>>(S0A, S0B, seq, 0, WG0, gb0, WC0, cb0);

    // merged pairs: dispatch k runs L1(t=k) and L0(t=k+1)
    unsigned short *h0r = S0B, *h0w = S0A, *h1r = S1A, *h1w = S1B;
    for (int t = 0; t < TT - 1; ++t) {
        step_pair<<<grid2, block, 0, stream>>>(h1r, h1w, h0r, h0w, seq, t + 1,
                                               WG0, gb0, WC0, cb0,
                                               WG1, gb1, WC1, cb1);
        unsigned short* tmp;
        tmp = h0r; h0r = h0w; h0w = tmp;
        tmp = h1r; h1r = h1w; h1w = tmp;
    }
    // final: L1(15) reads h1r + h0r (h0'(15)), emits NCHW fp32 out
    cell_l1_emit<<<grid1, block, 0, stream>>>(h1r, h0r, WG1, gb1, WC1, cb1, out);
}